// Round 12
// baseline (189.358 us; speedup 1.0000x reference)
//
#include <hip/hip_runtime.h>
#include <math.h>

#define Wd 160
#define Hd 128
#define Cd 32
#define Dd 64
#define HWd (Hd * Wd)
#define PV_OFF (3 * HWd)
#define VW_OFF (67 * HWd)

// ws float offsets (params)
#define WS_ROT 0      // 4 views * 12 floats (rot row-major 9, trans 3)
#define WS_A0 64
#define WS_B0 80
#define WS_W1 96
#define WS_B1 224
#define WS_W2 232
#define WS_BIAS2 240
#define WS_CW0 241
#define WS_CB0 249
#define WS_CW1 257
#define WS_CB1 265
#define WS_TOTAL 272
// pixelwise-net LUT: 2048 floats at ws offset 1024
#define WS_LUT 1024
#define LUT_N 2048
#define LUT_LO (-4.0f)
#define LUT_INV_STEP ((float)LUT_N / 8.0f)  // 256.0
// f32 transposed features start at float offset 4096 (byte 16384)
#define WS_FEAT_OFF 4096

#if __has_builtin(__builtin_amdgcn_rcpf)
#define RCPF(x) __builtin_amdgcn_rcpf(x)   // v_rcp_f32, ~1ulp
#else
#define RCPF(x) (1.0f / (x))
#endif

__global__ void setup_kernel(const float* __restrict__ pm,
                             const float* __restrict__ pw_w0, const float* __restrict__ pw_g0,
                             const float* __restrict__ pw_b0, const float* __restrict__ pw_w1,
                             const float* __restrict__ pw_g1, const float* __restrict__ pw_b1,
                             const float* __restrict__ pw_w2, const float* __restrict__ pw_bias2,
                             const float* __restrict__ cr_w0, const float* __restrict__ cr_b0,
                             const float* __restrict__ cr_w1, const float* __restrict__ cr_b1,
                             float* __restrict__ wsf)
{
    if (blockIdx.x != 0 || threadIdx.x != 0) return;

    double F[5][16];
    for (int v = 0; v < 5; ++v) {
        const float* E = pm + v * 32;       // [v][0][4][4]
        const float* K = pm + v * 32 + 16;  // [v][1][4][4]
        double f[16];
        for (int i = 0; i < 16; ++i) f[i] = (double)E[i];
        for (int i = 0; i < 3; ++i)
            for (int j = 0; j < 4; ++j) {
                double s = 0.0;
                for (int k = 0; k < 3; ++k) s += (double)K[i * 4 + k] * (double)E[k * 4 + j];
                f[i * 4 + j] = s;
            }
        for (int i = 0; i < 16; ++i) F[v][i] = f[i];
    }

    double A[4][8];
    for (int i = 0; i < 4; ++i)
        for (int j = 0; j < 4; ++j) { A[i][j] = F[0][i * 4 + j]; A[i][j + 4] = (i == j) ? 1.0 : 0.0; }
    for (int col = 0; col < 4; ++col) {
        int piv = col; double best = fabs(A[col][col]);
        for (int r = col + 1; r < 4; ++r) { double a = fabs(A[r][col]); if (a > best) { best = a; piv = r; } }
        if (piv != col)
            for (int j = 0; j < 8; ++j) { double t = A[col][j]; A[col][j] = A[piv][j]; A[piv][j] = t; }
        double inv = 1.0 / A[col][col];
        for (int j = 0; j < 8; ++j) A[col][j] *= inv;
        for (int r = 0; r < 4; ++r)
            if (r != col) {
                double m = A[r][col];
                for (int j = 0; j < 8; ++j) A[r][j] -= m * A[col][j];
            }
    }
    double inv0[16];
    for (int i = 0; i < 4; ++i)
        for (int j = 0; j < 4; ++j) inv0[i * 4 + j] = A[i][j + 4];

    for (int v = 1; v < 5; ++v) {
        double P[16];
        for (int i = 0; i < 4; ++i)
            for (int j = 0; j < 4; ++j) {
                double s = 0.0;
                for (int k = 0; k < 4; ++k) s += F[v][i * 4 + k] * inv0[k * 4 + j];
                P[i * 4 + j] = s;
            }
        float* o = wsf + WS_ROT + (v - 1) * 12;
        o[0] = (float)P[0];  o[1] = (float)P[1];  o[2] = (float)P[2];
        o[3] = (float)P[4];  o[4] = (float)P[5];  o[5] = (float)P[6];
        o[6] = (float)P[8];  o[7] = (float)P[9];  o[8] = (float)P[10];
        o[9] = (float)P[3];  o[10] = (float)P[7]; o[11] = (float)P[11];
    }

    const float rs = rsqrtf(1.0f + 1e-5f);
    for (int j = 0; j < 16; ++j) {
        wsf[WS_A0 + j] = pw_w0[j] * pw_g0[j] * rs;
        wsf[WS_B0 + j] = pw_b0[j];
    }
    for (int k = 0; k < 8; ++k) {
        float sk = pw_g1[k] * rs;
        for (int j = 0; j < 16; ++j) wsf[WS_W1 + k * 16 + j] = pw_w1[k * 16 + j] * sk;
        wsf[WS_B1 + k] = pw_b1[k];
        wsf[WS_W2 + k] = pw_w2[k];
    }
    wsf[WS_BIAS2] = pw_bias2[0];
    for (int j = 0; j < 8; ++j) {
        wsf[WS_CW0 + j] = cr_w0[j];
        wsf[WS_CB0 + j] = cr_b0[j];
        wsf[WS_CW1 + j] = cr_w1[j];
    }
    wsf[WS_CB1] = cr_b1[0];
}

// Tabulate the pixelwise net f(sim): piecewise-linear -> LUT + lerp near-exact
__global__ __launch_bounds__(256) void lut_kernel(
    const float* __restrict__ pw_w0, const float* __restrict__ pw_g0,
    const float* __restrict__ pw_b0, const float* __restrict__ pw_w1,
    const float* __restrict__ pw_g1, const float* __restrict__ pw_b1,
    const float* __restrict__ pw_w2, const float* __restrict__ pw_bias2,
    float* __restrict__ wsf)
{
    const int i = blockIdx.x * 256 + threadIdx.x;
    if (i >= LUT_N) return;
    const float x = LUT_LO + (float)i * (8.0f / (float)LUT_N);
    const float rs = rsqrtf(1.0f + 1e-5f);
    float x0v[16];
#pragma unroll
    for (int j = 0; j < 16; ++j)
        x0v[j] = fmaxf(pw_w0[j] * pw_g0[j] * rs * x + pw_b0[j], 0.f);
    float y = pw_bias2[0];
#pragma unroll
    for (int k = 0; k < 8; ++k) {
        float d0 = 0.f;
#pragma unroll
        for (int j = 0; j < 16; ++j) d0 += pw_w1[k * 16 + j] * x0v[j];
        const float x1 = fmaxf(d0 * pw_g1[k] * rs + pw_b1[k], 0.f);
        y += pw_w2[k] * x1;
    }
    wsf[WS_LUT + i] = y;
}

// features [5][32][HW] -> featT [5][HW][32] f32, LDS-tiled (128 px per block)
__global__ __launch_bounds__(256) void transpose_kernel(const float* __restrict__ f,
                                                        float* __restrict__ ft)
{
    __shared__ float lds[32][129];
    const int v = blockIdx.y;
    const int base = blockIdx.x * 128;
    const int tid = threadIdx.x;
    const float* src = f + (size_t)v * Cd * HWd;
#pragma unroll
    for (int it = 0; it < 16; ++it) {
        const int c = it * 2 + (tid >> 7);
        const int px = tid & 127;
        lds[c][px] = src[c * HWd + base + px];
    }
    __syncthreads();
    float* dst = ft + (size_t)v * HWd * Cd;
#pragma unroll
    for (int it = 0; it < 16; ++it) {
        const int c = tid & 31;
        const int px = (tid >> 5) + it * 8;
        dst[(size_t)(base + px) * Cd + c] = lds[c][px];
    }
}

// Main kernel: wave = pixel. (round-8 structure = measured best, 152us)
// Phase A (per view): lane = depth -> taps computed once per depth.
//   Tap indices packed: i00 + (d01 | d10<<16); d11 = d01+d10 (exact identity,
//   deltas non-negative since clamp is monotone) -> 2 index broadcasts not 4.
// Phase B (per depth-octet g): lane = q*8+c8; taps broadcast from lane g*8+q
//   via dynamic __shfl (ds_bpermute); 4 coalesced float4 loads per octet;
//   dot + 3-shuffle reduce; pixelwise-net via LDS LUT.
// NOTE: no min-waves clamp in __launch_bounds__ -- forcing 8 waves/EU made the
// allocator clamp to 32 VGPR and spill 843 MB/launch (round-9 regression).
// NOTE: view loop stays unroll 1 -- unroll 2 cost 16 VGPR -> 5 waves/SIMD and
// regressed 157->164us (round-11).
__global__ __launch_bounds__(256) void depthnet_main_t(
    const float* __restrict__ featT,   // [5][HW][32] f32
    const float* __restrict__ depth_values,
    const float* __restrict__ wsf,
    float* __restrict__ out)
{
    __shared__ float sm[WS_TOTAL];
    __shared__ float lut[LUT_N];
    __shared__ __align__(16) float refs[4][32];
    const int tid = threadIdx.x;
    for (int i = tid; i < WS_TOTAL; i += 256) sm[i] = wsf[i];
    for (int i = tid; i < LUT_N; i += 256) lut[i] = wsf[WS_LUT + i];

    // XCD-aware swizzle (5120 blocks % 8 == 0 -> bijective)
    const int bid = blockIdx.x;
    const int swz = (bid & 7) * (gridDim.x >> 3) + (bid >> 3);
    const int pixbase = swz * 4;

    if (tid < 128) {
        const int w = tid >> 5, c = tid & 31;
        refs[w][c] = featT[(size_t)(pixbase + w) * Cd + c];
    }
    __syncthreads();

    const int wv = tid >> 6;        // wave index in block -> pixel
    const int lane = tid & 63;
    const int q  = lane >> 3;       // depth slot within octet group (0..7)
    const int c8 = lane & 7;        // channel chunk (0..7), 4 floats each
    const int pix = pixbase + wv;
    const float xf = (float)(pix % Wd);
    const float yf = (float)(pix / Wd);

    // this lane's ref-feature chunk (4 channels)
    const float4 rfc = ((const float4*)refs[wv])[c8];

    // depth for lane-as-depth-index (phase A), per-(g,q) depths via shuffle
    const float depL = depth_values[lane * HWd + pix];
    float dep[8];
#pragma unroll
    for (int g = 0; g < 8; ++g) dep[g] = __shfl(depL, g * 8 + q, 64);

    float sim_sum[8];
#pragma unroll
    for (int g = 0; g < 8; ++g) sim_sum[g] = 0.f;
    float w_sum = 1e-5f;

#pragma unroll 1
    for (int v = 0; v < 4; ++v) {
        const float4* __restrict__ src4 = (const float4*)(featT + (size_t)(v + 1) * HWd * Cd);
        const float* m = &sm[WS_ROT + v * 12];
        const float rX = m[0] * xf + m[1] * yf + m[2];
        const float rY = m[3] * xf + m[4] * yf + m[5];
        const float rZ = m[6] * xf + m[7] * yf + m[8];
        const float tx = m[9], ty = m[10], tz = m[11];

        // ---- Phase A: taps for depth = lane (computed once per depth) ----
        float w00L, w01L, w10L, w11L;
        int i00L, pkL;
        {
            const float X = rX * depL + tx;
            const float Y = rY * depL + ty;
            const float Z = rZ * depL + tz;
            const float invZ = RCPF(Z);
            const float pxf = X * invZ;
            const float pyf = Y * invZ;
            const float fx0 = floorf(pxf), fy0 = floorf(pyf);
            const float wx1 = pxf - fx0, wy1 = pyf - fy0;
            const float wx0 = 1.f - wx1, wy0 = 1.f - wy1;
            const float fx1 = fx0 + 1.f, fy1 = fy0 + 1.f;
            const float bx0 = (fx0 >= 0.f && fx0 <= (float)(Wd - 1)) ? 1.f : 0.f;
            const float bx1 = (fx1 >= 0.f && fx1 <= (float)(Wd - 1)) ? 1.f : 0.f;
            const float by0 = (fy0 >= 0.f && fy0 <= (float)(Hd - 1)) ? 1.f : 0.f;
            const float by1 = (fy1 >= 0.f && fy1 <= (float)(Hd - 1)) ? 1.f : 0.f;
            w00L = wx0 * wy0 * bx0 * by0;
            w01L = wx1 * wy0 * bx1 * by0;
            w10L = wx0 * wy1 * bx0 * by1;
            w11L = wx1 * wy1 * bx1 * by1;
            const int ix0 = (int)fminf(fmaxf(fx0, 0.f), (float)(Wd - 1));
            const int ix1 = (int)fminf(fmaxf(fx1, 0.f), (float)(Wd - 1));
            const int iy0 = (int)fminf(fmaxf(fy0, 0.f), (float)(Hd - 1));
            const int iy1 = (int)fminf(fmaxf(fy1, 0.f), (float)(Hd - 1));
            i00L = (iy0 * Wd + ix0) * 8;
            // deltas: d01 in {0,8}, d10 in {0,1280}; d11 = d01+d10 exactly
            pkL = ((ix1 - ix0) * 8) | (((iy1 - iy0) * Wd * 8) << 16);
        }

        // ---- Phase B: per octet-group gather + dot ----
        float simv[8];
        float ymax = -3.0e38f;
#pragma unroll
        for (int g = 0; g < 8; ++g) {
            const int sl = g * 8 + q;  // source lane holding this depth's taps
            const float w00 = __shfl(w00L, sl, 64);
            const float w01 = __shfl(w01L, sl, 64);
            const float w10 = __shfl(w10L, sl, 64);
            const float w11 = __shfl(w11L, sl, 64);
            const int b00 = __shfl(i00L, sl, 64);
            const int pk  = __shfl(pkL, sl, 64);
            const int d01 = pk & 0xffff;
            const int d10 = pk >> 16;
            const float4 t00 = src4[b00 + c8];
            const float4 t01 = src4[b00 + d01 + c8];
            const float4 t10 = src4[b00 + d10 + c8];
            const float4 t11 = src4[b00 + d01 + d10 + c8];
            float4 a;
            a.x = t00.x * w00 + t01.x * w01 + t10.x * w10 + t11.x * w11;
            a.y = t00.y * w00 + t01.y * w01 + t10.y * w10 + t11.y * w11;
            a.z = t00.z * w00 + t01.z * w01 + t10.z * w10 + t11.z * w11;
            a.w = t00.w * w00 + t01.w * w01 + t10.w * w10 + t11.w * w11;
            float p = a.x * rfc.x + a.y * rfc.y + a.z * rfc.z + a.w * rfc.w;
            p += __shfl_xor(p, 1, 64);
            p += __shfl_xor(p, 2, 64);
            p += __shfl_xor(p, 4, 64);
            const float sim = p * (1.f / 32.f);
            simv[g] = sim;
            const float tt = fminf(fmaxf((sim - LUT_LO) * LUT_INV_STEP, 0.f), (float)(LUT_N - 2));
            const int i0 = (int)tt;
            const float fr = tt - (float)i0;
            const float yv = fmaf(lut[i0 + 1] - lut[i0], fr, lut[i0]);
            ymax = fmaxf(ymax, yv);
        }
        // max over depth slots q
        ymax = fmaxf(ymax, __shfl_xor(ymax, 8, 64));
        ymax = fmaxf(ymax, __shfl_xor(ymax, 16, 64));
        ymax = fmaxf(ymax, __shfl_xor(ymax, 32, 64));
        const float vw = 1.f / (1.f + expf(-ymax));
#pragma unroll
        for (int g = 0; g < 8; ++g) sim_sum[g] += simv[g] * vw;
        w_sum += vw;
        if (lane == 0) out[VW_OFF + v * HWd + pix] = vw;
    }

    float simil[8];
#pragma unroll
    for (int g = 0; g < 8; ++g) simil[g] = sim_sum[g] / w_sum;

    // argmax similarity (first index on ties) -> similarity_depth
    float bv = simil[0]; int bdi = q; float bdep = dep[0];
#pragma unroll
    for (int g = 1; g < 8; ++g)
        if (simil[g] > bv) { bv = simil[g]; bdi = g * 8 + q; bdep = dep[g]; }
#pragma unroll
    for (int o = 8; o <= 32; o <<= 1) {
        const float ov = __shfl_xor(bv, o, 64);
        const int   odi = __shfl_xor(bdi, o, 64);
        const float odep = __shfl_xor(bdep, o, 64);
        if (ov > bv || (ov == bv && odi < bdi)) { bv = ov; bdi = odi; bdep = odep; }
    }
    const float sim_depth = bdep;

    // cr net 1->8->1 per depth
    float y2[8];
    {
        const float cb1 = sm[WS_CB1];
#pragma unroll
        for (int g = 0; g < 8; ++g) y2[g] = cb1;
    }
#pragma unroll
    for (int j = 0; j < 8; ++j) {
        const float a = sm[WS_CW0 + j];
        const float b = sm[WS_CB0 + j];
        const float c = sm[WS_CW1 + j];
#pragma unroll
        for (int g = 0; g < 8; ++g)
            y2[g] += c * fmaxf(a * simil[g] + b, 0.f);
    }

    // softmax over 64 depths (8 regs x 8 q-slots)
    float m2 = y2[0];
#pragma unroll
    for (int g = 1; g < 8; ++g) m2 = fmaxf(m2, y2[g]);
    m2 = fmaxf(m2, __shfl_xor(m2, 8, 64));
    m2 = fmaxf(m2, __shfl_xor(m2, 16, 64));
    m2 = fmaxf(m2, __shfl_xor(m2, 32, 64));
    float e[8]; float s = 0.f;
#pragma unroll
    for (int g = 0; g < 8; ++g) { e[g] = expf(y2[g] - m2); s += e[g]; }
    s += __shfl_xor(s, 8, 64);
    s += __shfl_xor(s, 16, 64);
    s += __shfl_xor(s, 32, 64);
    const float invs = 1.f / s;

    if (c8 == 0) {
#pragma unroll
        for (int g = 0; g < 8; ++g)
            out[PV_OFF + (g * 8 + q) * HWd + pix] = e[g] * invs;
    }

    // argmax y2 (== argmax prob) -> depth WTA; conf = max prob
    float bv2 = y2[0]; int bdi2 = q; float bdep2 = dep[0];
#pragma unroll
    for (int g = 1; g < 8; ++g)
        if (y2[g] > bv2) { bv2 = y2[g]; bdi2 = g * 8 + q; bdep2 = dep[g]; }
#pragma unroll
    for (int o = 8; o <= 32; o <<= 1) {
        const float ov = __shfl_xor(bv2, o, 64);
        const int   odi = __shfl_xor(bdi2, o, 64);
        const float odep = __shfl_xor(bdep2, o, 64);
        if (ov > bv2 || (ov == bv2 && odi < bdi2)) { bv2 = ov; bdi2 = odi; bdep2 = odep; }
    }
    const float depth_o = bdep2;
    const float conf = expf(bv2 - m2) * invs;

    if (lane == 0) {
        out[pix] = depth_o;
        out[HWd + pix] = sim_depth;
        out[2 * HWd + pix] = conf;
    }
}

// ---------------- fallback (round-1) main kernel, used if ws too small ----------
__global__ __launch_bounds__(256) void depthnet_main(
    const float* __restrict__ features,
    const float* __restrict__ depth_values,
    const float* __restrict__ wsf,
    float* __restrict__ out)
{
    __shared__ float sm[WS_TOTAL];
    const int tid = threadIdx.x;
    for (int i = tid; i < WS_TOTAL; i += 256) sm[i] = wsf[i];
    __syncthreads();

    const int pix = (blockIdx.x * 256 + tid) >> 6;
    const int lane = tid & 63;
    const float xf = (float)(pix % Wd);
    const float yf = (float)(pix / Wd);

    float refc[Cd];
#pragma unroll
    for (int c = 0; c < Cd; ++c) refc[c] = features[c * HWd + pix];

    const float dep = depth_values[lane * HWd + pix];

    float sim_sum = 0.f;
    float w_sum = 1e-5f;

    for (int v = 0; v < 4; ++v) {
        const float* __restrict__ src = features + (v + 1) * Cd * HWd;
        const float* m = &sm[WS_ROT + v * 12];
        const float rX = m[0] * xf + m[1] * yf + m[2];
        const float rY = m[3] * xf + m[4] * yf + m[5];
        const float rZ = m[6] * xf + m[7] * yf + m[8];
        const float X = rX * dep + m[9];
        const float Y = rY * dep + m[10];
        const float Z = rZ * dep + m[11];
        const float pxf = X / Z;
        const float pyf = Y / Z;
        const float fx0 = floorf(pxf), fy0 = floorf(pyf);
        const float wx1 = pxf - fx0, wy1 = pyf - fy0;
        const float wx0 = 1.f - wx1, wy0 = 1.f - wy1;
        const float fx1 = fx0 + 1.f, fy1 = fy0 + 1.f;
        const float bx0 = (fx0 >= 0.f && fx0 <= (float)(Wd - 1)) ? 1.f : 0.f;
        const float bx1 = (fx1 >= 0.f && fx1 <= (float)(Wd - 1)) ? 1.f : 0.f;
        const float by0 = (fy0 >= 0.f && fy0 <= (float)(Hd - 1)) ? 1.f : 0.f;
        const float by1 = (fy1 >= 0.f && fy1 <= (float)(Hd - 1)) ? 1.f : 0.f;
        const float w00 = wx0 * wy0 * bx0 * by0;
        const float w01 = wx1 * wy0 * bx1 * by0;
        const float w10 = wx0 * wy1 * bx0 * by1;
        const float w11 = wx1 * wy1 * bx1 * by1;
        const int ix0 = (int)fminf(fmaxf(fx0, 0.f), (float)(Wd - 1));
        const int ix1 = (int)fminf(fmaxf(fx1, 0.f), (float)(Wd - 1));
        const int iy0 = (int)fminf(fmaxf(fy0, 0.f), (float)(Hd - 1));
        const int iy1 = (int)fminf(fmaxf(fy1, 0.f), (float)(Hd - 1));
        const int i00 = iy0 * Wd + ix0;
        const int i01 = iy0 * Wd + ix1;
        const int i10 = iy1 * Wd + ix0;
        const int i11 = iy1 * Wd + ix1;

        float acc = 0.f;
#pragma unroll
        for (int c = 0; c < Cd; ++c) {
            const float* p = src + c * HWd;
            const float bil = p[i00] * w00 + p[i01] * w01 + p[i10] * w10 + p[i11] * w11;
            acc += bil * refc[c];
        }
        const float sim = acc * (1.f / 32.f);

        float x0v[16];
#pragma unroll
        for (int j = 0; j < 16; ++j)
            x0v[j] = fmaxf(sm[WS_A0 + j] * sim + sm[WS_B0 + j], 0.f);
        float yv = sm[WS_BIAS2];
#pragma unroll
        for (int k = 0; k < 8; ++k) {
            float d0 = 0.f;
#pragma unroll
            for (int j = 0; j < 16; ++j) d0 += sm[WS_W1 + k * 16 + j] * x0v[j];
            const float x1 = fmaxf(d0 + sm[WS_B1 + k], 0.f);
            yv += sm[WS_W2 + k] * x1;
        }
        float ymax = yv;
#pragma unroll
        for (int o = 32; o >= 1; o >>= 1) ymax = fmaxf(ymax, __shfl_xor(ymax, o, 64));
        const float vw = 1.f / (1.f + expf(-ymax));
        sim_sum += sim * vw;
        w_sum += vw;
        if (lane == 0) out[VW_OFF + v * HWd + pix] = vw;
    }

    const float simil = sim_sum / w_sum;

    float bv = simil; int bi = lane;
#pragma unroll
    for (int o = 32; o >= 1; o >>= 1) {
        const float ov = __shfl_xor(bv, o, 64);
        const int oi = __shfl_xor(bi, o, 64);
        if (ov > bv || (ov == bv && oi < bi)) { bv = ov; bi = oi; }
    }
    const float sim_depth = __shfl(dep, bi, 64);

    float y2 = sm[WS_CB1];
#pragma unroll
    for (int j = 0; j < 8; ++j) {
        const float h = fmaxf(sm[WS_CW0 + j] * simil + sm[WS_CB0 + j], 0.f);
        y2 += sm[WS_CW1 + j] * h;
    }
    float m2 = y2;
#pragma unroll
    for (int o = 32; o >= 1; o >>= 1) m2 = fmaxf(m2, __shfl_xor(m2, o, 64));
    const float e = expf(y2 - m2);
    float s = e;
#pragma unroll
    for (int o = 32; o >= 1; o >>= 1) s += __shfl_xor(s, o, 64);
    const float prob = e / s;
    out[PV_OFF + lane * HWd + pix] = prob;

    float bv2 = y2; int bi2 = lane;
#pragma unroll
    for (int o = 32; o >= 1; o >>= 1) {
        const float ov = __shfl_xor(bv2, o, 64);
        const int oi = __shfl_xor(bi2, o, 64);
        if (ov > bv2 || (ov == bv2 && oi < bi2)) { bv2 = ov; bi2 = oi; }
    }
    const float depth_o = __shfl(dep, bi2, 64);
    const float conf = 1.f / s;

    if (lane == 0) {
        out[pix] = depth_o;
        out[HWd + pix] = sim_depth;
        out[2 * HWd + pix] = conf;
    }
}

extern "C" void kernel_launch(void* const* d_in, const int* in_sizes, int n_in,
                              void* d_out, int out_size, void* d_ws, size_t ws_size,
                              hipStream_t stream)
{
    const float* features     = (const float*)d_in[0];
    const float* pm           = (const float*)d_in[1];
    const float* depth_values = (const float*)d_in[2];
    const float* pw_w0   = (const float*)d_in[4];
    const float* pw_g0   = (const float*)d_in[5];
    const float* pw_b0   = (const float*)d_in[6];
    const float* pw_w1   = (const float*)d_in[7];
    const float* pw_g1   = (const float*)d_in[8];
    const float* pw_b1   = (const float*)d_in[9];
    const float* pw_w2   = (const float*)d_in[10];
    const float* pw_bias2= (const float*)d_in[11];
    const float* cr_w0   = (const float*)d_in[12];
    const float* cr_b0   = (const float*)d_in[13];
    const float* cr_w1   = (const float*)d_in[14];
    const float* cr_b1   = (const float*)d_in[15];
    float* wsf = (float*)d_ws;
    float* out = (float*)d_out;

    hipLaunchKernelGGL(setup_kernel, dim3(1), dim3(64), 0, stream,
                       pm, pw_w0, pw_g0, pw_b0, pw_w1, pw_g1, pw_b1, pw_w2, pw_bias2,
                       cr_w0, cr_b0, cr_w1, cr_b1, wsf);

    const size_t need = (size_t)WS_FEAT_OFF * 4 + (size_t)5 * HWd * Cd * 4;
    if (ws_size >= need) {
        float* featT = wsf + WS_FEAT_OFF;
        hipLaunchKernelGGL(lut_kernel, dim3(LUT_N / 256), dim3(256), 0, stream,
                           pw_w0, pw_g0, pw_b0, pw_w1, pw_g1, pw_b1, pw_w2, pw_bias2, wsf);
        hipLaunchKernelGGL(transpose_kernel, dim3(HWd / 128, 5), dim3(256), 0, stream,
                           features, featT);
        hipLaunchKernelGGL(depthnet_main_t, dim3(HWd / 4), dim3(256), 0, stream,
                           featT, depth_values, wsf, out);
    } else {
        hipLaunchKernelGGL(depthnet_main, dim3(HWd / 4), dim3(256), 0, stream,
                           features, depth_values, wsf, out);
    }
}

// Round 13
// 155.288 us; speedup vs baseline: 1.2194x; 1.2194x over previous
//
#include <hip/hip_runtime.h>
#include <math.h>

#define Wd 160
#define Hd 128
#define Cd 32
#define Dd 64
#define HWd (Hd * Wd)
#define PV_OFF (3 * HWd)
#define VW_OFF (67 * HWd)

// ws float offsets (params)
#define WS_ROT 0      // 4 views * 12 floats (rot row-major 9, trans 3)
#define WS_A0 64
#define WS_B0 80
#define WS_W1 96
#define WS_B1 224
#define WS_W2 232
#define WS_BIAS2 240
#define WS_CW0 241
#define WS_CB0 249
#define WS_CW1 257
#define WS_CB1 265
#define WS_TOTAL 272
// pixelwise-net LUT: 2048 floats at ws offset 1024
#define WS_LUT 1024
#define LUT_N 2048
#define LUT_LO (-4.0f)
#define LUT_INV_STEP ((float)LUT_N / 8.0f)  // 256.0
// f32 transposed features start at float offset 4096 (byte 16384)
#define WS_FEAT_OFF 4096

#if __has_builtin(__builtin_amdgcn_rcpf)
#define RCPF(x) __builtin_amdgcn_rcpf(x)   // v_rcp_f32, ~1ulp
#else
#define RCPF(x) (1.0f / (x))
#endif

__global__ void setup_kernel(const float* __restrict__ pm,
                             const float* __restrict__ pw_w0, const float* __restrict__ pw_g0,
                             const float* __restrict__ pw_b0, const float* __restrict__ pw_w1,
                             const float* __restrict__ pw_g1, const float* __restrict__ pw_b1,
                             const float* __restrict__ pw_w2, const float* __restrict__ pw_bias2,
                             const float* __restrict__ cr_w0, const float* __restrict__ cr_b0,
                             const float* __restrict__ cr_w1, const float* __restrict__ cr_b1,
                             float* __restrict__ wsf)
{
    if (blockIdx.x != 0 || threadIdx.x != 0) return;

    double F[5][16];
    for (int v = 0; v < 5; ++v) {
        const float* E = pm + v * 32;       // [v][0][4][4]
        const float* K = pm + v * 32 + 16;  // [v][1][4][4]
        double f[16];
        for (int i = 0; i < 16; ++i) f[i] = (double)E[i];
        for (int i = 0; i < 3; ++i)
            for (int j = 0; j < 4; ++j) {
                double s = 0.0;
                for (int k = 0; k < 3; ++k) s += (double)K[i * 4 + k] * (double)E[k * 4 + j];
                f[i * 4 + j] = s;
            }
        for (int i = 0; i < 16; ++i) F[v][i] = f[i];
    }

    double A[4][8];
    for (int i = 0; i < 4; ++i)
        for (int j = 0; j < 4; ++j) { A[i][j] = F[0][i * 4 + j]; A[i][j + 4] = (i == j) ? 1.0 : 0.0; }
    for (int col = 0; col < 4; ++col) {
        int piv = col; double best = fabs(A[col][col]);
        for (int r = col + 1; r < 4; ++r) { double a = fabs(A[r][col]); if (a > best) { best = a; piv = r; } }
        if (piv != col)
            for (int j = 0; j < 8; ++j) { double t = A[col][j]; A[col][j] = A[piv][j]; A[piv][j] = t; }
        double inv = 1.0 / A[col][col];
        for (int j = 0; j < 8; ++j) A[col][j] *= inv;
        for (int r = 0; r < 4; ++r)
            if (r != col) {
                double m = A[r][col];
                for (int j = 0; j < 8; ++j) A[r][j] -= m * A[col][j];
            }
    }
    double inv0[16];
    for (int i = 0; i < 4; ++i)
        for (int j = 0; j < 4; ++j) inv0[i * 4 + j] = A[i][j + 4];

    for (int v = 1; v < 5; ++v) {
        double P[16];
        for (int i = 0; i < 4; ++i)
            for (int j = 0; j < 4; ++j) {
                double s = 0.0;
                for (int k = 0; k < 4; ++k) s += F[v][i * 4 + k] * inv0[k * 4 + j];
                P[i * 4 + j] = s;
            }
        float* o = wsf + WS_ROT + (v - 1) * 12;
        o[0] = (float)P[0];  o[1] = (float)P[1];  o[2] = (float)P[2];
        o[3] = (float)P[4];  o[4] = (float)P[5];  o[5] = (float)P[6];
        o[6] = (float)P[8];  o[7] = (float)P[9];  o[8] = (float)P[10];
        o[9] = (float)P[3];  o[10] = (float)P[7]; o[11] = (float)P[11];
    }

    const float rs = rsqrtf(1.0f + 1e-5f);
    for (int j = 0; j < 16; ++j) {
        wsf[WS_A0 + j] = pw_w0[j] * pw_g0[j] * rs;
        wsf[WS_B0 + j] = pw_b0[j];
    }
    for (int k = 0; k < 8; ++k) {
        float sk = pw_g1[k] * rs;
        for (int j = 0; j < 16; ++j) wsf[WS_W1 + k * 16 + j] = pw_w1[k * 16 + j] * sk;
        wsf[WS_B1 + k] = pw_b1[k];
        wsf[WS_W2 + k] = pw_w2[k];
    }
    wsf[WS_BIAS2] = pw_bias2[0];
    for (int j = 0; j < 8; ++j) {
        wsf[WS_CW0 + j] = cr_w0[j];
        wsf[WS_CB0 + j] = cr_b0[j];
        wsf[WS_CW1 + j] = cr_w1[j];
    }
    wsf[WS_CB1] = cr_b1[0];
}

// Tabulate the pixelwise net f(sim): piecewise-linear -> LUT + lerp near-exact
__global__ __launch_bounds__(256) void lut_kernel(
    const float* __restrict__ pw_w0, const float* __restrict__ pw_g0,
    const float* __restrict__ pw_b0, const float* __restrict__ pw_w1,
    const float* __restrict__ pw_g1, const float* __restrict__ pw_b1,
    const float* __restrict__ pw_w2, const float* __restrict__ pw_bias2,
    float* __restrict__ wsf)
{
    const int i = blockIdx.x * 256 + threadIdx.x;
    if (i >= LUT_N) return;
    const float x = LUT_LO + (float)i * (8.0f / (float)LUT_N);
    const float rs = rsqrtf(1.0f + 1e-5f);
    float x0v[16];
#pragma unroll
    for (int j = 0; j < 16; ++j)
        x0v[j] = fmaxf(pw_w0[j] * pw_g0[j] * rs * x + pw_b0[j], 0.f);
    float y = pw_bias2[0];
#pragma unroll
    for (int k = 0; k < 8; ++k) {
        float d0 = 0.f;
#pragma unroll
        for (int j = 0; j < 16; ++j) d0 += pw_w1[k * 16 + j] * x0v[j];
        const float x1 = fmaxf(d0 * pw_g1[k] * rs + pw_b1[k], 0.f);
        y += pw_w2[k] * x1;
    }
    wsf[WS_LUT + i] = y;
}

// features [5][32][HW] -> featT [5][HW][32] f32, LDS-tiled (128 px per block)
__global__ __launch_bounds__(256) void transpose_kernel(const float* __restrict__ f,
                                                        float* __restrict__ ft)
{
    __shared__ float lds[32][129];
    const int v = blockIdx.y;
    const int base = blockIdx.x * 128;
    const int tid = threadIdx.x;
    const float* src = f + (size_t)v * Cd * HWd;
#pragma unroll
    for (int it = 0; it < 16; ++it) {
        const int c = it * 2 + (tid >> 7);
        const int px = tid & 127;
        lds[c][px] = src[c * HWd + base + px];
    }
    __syncthreads();
    float* dst = ft + (size_t)v * HWd * Cd;
#pragma unroll
    for (int it = 0; it < 16; ++it) {
        const int c = tid & 31;
        const int px = (tid >> 5) + it * 8;
        dst[(size_t)(base + px) * Cd + c] = lds[c][px];
    }
}

// Main kernel: wave = pixel.  (byte-exact round-8 configuration, measured 152us)
// Phase A (per view): lane = depth -> compute 4 bilinear weights + 4 float4-base
//   indices ONCE per depth.
// Phase B (per depth-octet g): lane = q*8+c8; tap params broadcast from lane
//   g*8+q via dynamic __shfl (ds_bpermute, DS pipe - idle anyway); 4 coalesced
//   float4 loads per octet; dot-chunk + 3-shuffle reduce.
// Measured dead-ends (do NOT revisit): launch_bounds(256,8) -> 32 VGPR clamp,
// 843MB spill (r9); dep-by-index -> neutral (r10); view unroll 2 -> 88 VGPR,
// 5 waves/SIMD, regress (r11); packed index broadcast -> 88 VGPR, regress (r12).
__global__ __launch_bounds__(256) void depthnet_main_t(
    const float* __restrict__ featT,   // [5][HW][32] f32
    const float* __restrict__ depth_values,
    const float* __restrict__ wsf,
    float* __restrict__ out)
{
    __shared__ float sm[WS_TOTAL];
    __shared__ float lut[LUT_N];
    __shared__ __align__(16) float refs[4][32];
    const int tid = threadIdx.x;
    for (int i = tid; i < WS_TOTAL; i += 256) sm[i] = wsf[i];
    for (int i = tid; i < LUT_N; i += 256) lut[i] = wsf[WS_LUT + i];

    // XCD-aware swizzle (5120 blocks % 8 == 0 -> bijective)
    const int bid = blockIdx.x;
    const int swz = (bid & 7) * (gridDim.x >> 3) + (bid >> 3);
    const int pixbase = swz * 4;

    if (tid < 128) {
        const int w = tid >> 5, c = tid & 31;
        refs[w][c] = featT[(size_t)(pixbase + w) * Cd + c];
    }
    __syncthreads();

    const int wv = tid >> 6;        // wave index in block -> pixel
    const int lane = tid & 63;
    const int q  = lane >> 3;       // depth slot within octet group (0..7)
    const int c8 = lane & 7;        // channel chunk (0..7), 4 floats each
    const int pix = pixbase + wv;
    const float xf = (float)(pix % Wd);
    const float yf = (float)(pix / Wd);

    // this lane's ref-feature chunk (4 channels)
    const float4 rfc = ((const float4*)refs[wv])[c8];

    // depth for lane-as-depth-index (phase A), and per-(g,q) depths via shuffle
    const float depL = depth_values[lane * HWd + pix];
    float dep[8];
#pragma unroll
    for (int g = 0; g < 8; ++g) dep[g] = __shfl(depL, g * 8 + q, 64);

    float sim_sum[8];
#pragma unroll
    for (int g = 0; g < 8; ++g) sim_sum[g] = 0.f;
    float w_sum = 1e-5f;

#pragma unroll 1
    for (int v = 0; v < 4; ++v) {
        const float4* __restrict__ src4 = (const float4*)(featT + (size_t)(v + 1) * HWd * Cd);
        const float* m = &sm[WS_ROT + v * 12];
        const float rX = m[0] * xf + m[1] * yf + m[2];
        const float rY = m[3] * xf + m[4] * yf + m[5];
        const float rZ = m[6] * xf + m[7] * yf + m[8];
        const float tx = m[9], ty = m[10], tz = m[11];

        // ---- Phase A: taps for depth = lane (computed once per depth) ----
        float w00L, w01L, w10L, w11L;
        int i00L, i01L, i10L, i11L;
        {
            const float X = rX * depL + tx;
            const float Y = rY * depL + ty;
            const float Z = rZ * depL + tz;
            const float invZ = RCPF(Z);
            const float pxf = X * invZ;
            const float pyf = Y * invZ;
            const float fx0 = floorf(pxf), fy0 = floorf(pyf);
            const float wx1 = pxf - fx0, wy1 = pyf - fy0;
            const float wx0 = 1.f - wx1, wy0 = 1.f - wy1;
            const float fx1 = fx0 + 1.f, fy1 = fy0 + 1.f;
            const float bx0 = (fx0 >= 0.f && fx0 <= (float)(Wd - 1)) ? 1.f : 0.f;
            const float bx1 = (fx1 >= 0.f && fx1 <= (float)(Wd - 1)) ? 1.f : 0.f;
            const float by0 = (fy0 >= 0.f && fy0 <= (float)(Hd - 1)) ? 1.f : 0.f;
            const float by1 = (fy1 >= 0.f && fy1 <= (float)(Hd - 1)) ? 1.f : 0.f;
            w00L = wx0 * wy0 * bx0 * by0;
            w01L = wx1 * wy0 * bx1 * by0;
            w10L = wx0 * wy1 * bx0 * by1;
            w11L = wx1 * wy1 * bx1 * by1;
            const int ix0 = (int)fminf(fmaxf(fx0, 0.f), (float)(Wd - 1));
            const int ix1 = (int)fminf(fmaxf(fx1, 0.f), (float)(Wd - 1));
            const int iy0 = (int)fminf(fmaxf(fy0, 0.f), (float)(Hd - 1));
            const int iy1 = (int)fminf(fmaxf(fy1, 0.f), (float)(Hd - 1));
            i00L = (iy0 * Wd + ix0) * 8;
            i01L = (iy0 * Wd + ix1) * 8;
            i10L = (iy1 * Wd + ix0) * 8;
            i11L = (iy1 * Wd + ix1) * 8;
        }

        // ---- Phase B: per octet-group gather + dot ----
        float simv[8];
        float ymax = -3.0e38f;
#pragma unroll
        for (int g = 0; g < 8; ++g) {
            const int sl = g * 8 + q;  // source lane holding this depth's taps
            const float w00 = __shfl(w00L, sl, 64);
            const float w01 = __shfl(w01L, sl, 64);
            const float w10 = __shfl(w10L, sl, 64);
            const float w11 = __shfl(w11L, sl, 64);
            const int b00 = __shfl(i00L, sl, 64);
            const int b01 = __shfl(i01L, sl, 64);
            const int b10 = __shfl(i10L, sl, 64);
            const int b11 = __shfl(i11L, sl, 64);
            const float4 t00 = src4[b00 + c8];
            const float4 t01 = src4[b01 + c8];
            const float4 t10 = src4[b10 + c8];
            const float4 t11 = src4[b11 + c8];
            float4 a;
            a.x = t00.x * w00 + t01.x * w01 + t10.x * w10 + t11.x * w11;
            a.y = t00.y * w00 + t01.y * w01 + t10.y * w10 + t11.y * w11;
            a.z = t00.z * w00 + t01.z * w01 + t10.z * w10 + t11.z * w11;
            a.w = t00.w * w00 + t01.w * w01 + t10.w * w10 + t11.w * w11;
            float p = a.x * rfc.x + a.y * rfc.y + a.z * rfc.z + a.w * rfc.w;
            p += __shfl_xor(p, 1, 64);
            p += __shfl_xor(p, 2, 64);
            p += __shfl_xor(p, 4, 64);
            const float sim = p * (1.f / 32.f);
            simv[g] = sim;
            const float tt = fminf(fmaxf((sim - LUT_LO) * LUT_INV_STEP, 0.f), (float)(LUT_N - 2));
            const int i0 = (int)tt;
            const float fr = tt - (float)i0;
            const float yv = fmaf(lut[i0 + 1] - lut[i0], fr, lut[i0]);
            ymax = fmaxf(ymax, yv);
        }
        // max over depth slots q
        ymax = fmaxf(ymax, __shfl_xor(ymax, 8, 64));
        ymax = fmaxf(ymax, __shfl_xor(ymax, 16, 64));
        ymax = fmaxf(ymax, __shfl_xor(ymax, 32, 64));
        const float vw = 1.f / (1.f + expf(-ymax));
#pragma unroll
        for (int g = 0; g < 8; ++g) sim_sum[g] += simv[g] * vw;
        w_sum += vw;
        if (lane == 0) out[VW_OFF + v * HWd + pix] = vw;
    }

    float simil[8];
#pragma unroll
    for (int g = 0; g < 8; ++g) simil[g] = sim_sum[g] / w_sum;

    // argmax similarity (first index on ties) -> similarity_depth
    float bv = simil[0]; int bdi = q; float bdep = dep[0];
#pragma unroll
    for (int g = 1; g < 8; ++g)
        if (simil[g] > bv) { bv = simil[g]; bdi = g * 8 + q; bdep = dep[g]; }
#pragma unroll
    for (int o = 8; o <= 32; o <<= 1) {
        const float ov = __shfl_xor(bv, o, 64);
        const int   odi = __shfl_xor(bdi, o, 64);
        const float odep = __shfl_xor(bdep, o, 64);
        if (ov > bv || (ov == bv && odi < bdi)) { bv = ov; bdi = odi; bdep = odep; }
    }
    const float sim_depth = bdep;

    // cr net 1->8->1 per depth
    float y2[8];
    {
        const float cb1 = sm[WS_CB1];
#pragma unroll
        for (int g = 0; g < 8; ++g) y2[g] = cb1;
    }
#pragma unroll
    for (int j = 0; j < 8; ++j) {
        const float a = sm[WS_CW0 + j];
        const float b = sm[WS_CB0 + j];
        const float c = sm[WS_CW1 + j];
#pragma unroll
        for (int g = 0; g < 8; ++g)
            y2[g] += c * fmaxf(a * simil[g] + b, 0.f);
    }

    // softmax over 64 depths (8 regs x 8 q-slots)
    float m2 = y2[0];
#pragma unroll
    for (int g = 1; g < 8; ++g) m2 = fmaxf(m2, y2[g]);
    m2 = fmaxf(m2, __shfl_xor(m2, 8, 64));
    m2 = fmaxf(m2, __shfl_xor(m2, 16, 64));
    m2 = fmaxf(m2, __shfl_xor(m2, 32, 64));
    float e[8]; float s = 0.f;
#pragma unroll
    for (int g = 0; g < 8; ++g) { e[g] = expf(y2[g] - m2); s += e[g]; }
    s += __shfl_xor(s, 8, 64);
    s += __shfl_xor(s, 16, 64);
    s += __shfl_xor(s, 32, 64);
    const float invs = 1.f / s;

    if (c8 == 0) {
#pragma unroll
        for (int g = 0; g < 8; ++g)
            out[PV_OFF + (g * 8 + q) * HWd + pix] = e[g] * invs;
    }

    // argmax y2 (== argmax prob) -> depth WTA; conf = max prob
    float bv2 = y2[0]; int bdi2 = q; float bdep2 = dep[0];
#pragma unroll
    for (int g = 1; g < 8; ++g)
        if (y2[g] > bv2) { bv2 = y2[g]; bdi2 = g * 8 + q; bdep2 = dep[g]; }
#pragma unroll
    for (int o = 8; o <= 32; o <<= 1) {
        const float ov = __shfl_xor(bv2, o, 64);
        const int   odi = __shfl_xor(bdi2, o, 64);
        const float odep = __shfl_xor(bdep2, o, 64);
        if (ov > bv2 || (ov == bv2 && odi < bdi2)) { bv2 = ov; bdi2 = odi; bdep2 = odep; }
    }
    const float depth_o = bdep2;
    const float conf = expf(bv2 - m2) * invs;

    if (lane == 0) {
        out[pix] = depth_o;
        out[HWd + pix] = sim_depth;
        out[2 * HWd + pix] = conf;
    }
}

// ---------------- fallback (round-1) main kernel, used if ws too small ----------
__global__ __launch_bounds__(256) void depthnet_main(
    const float* __restrict__ features,
    const float* __restrict__ depth_values,
    const float* __restrict__ wsf,
    float* __restrict__ out)
{
    __shared__ float sm[WS_TOTAL];
    const int tid = threadIdx.x;
    for (int i = tid; i < WS_TOTAL; i += 256) sm[i] = wsf[i];
    __syncthreads();

    const int pix = (blockIdx.x * 256 + tid) >> 6;
    const int lane = tid & 63;
    const float xf = (float)(pix % Wd);
    const float yf = (float)(pix / Wd);

    float refc[Cd];
#pragma unroll
    for (int c = 0; c < Cd; ++c) refc[c] = features[c * HWd + pix];

    const float dep = depth_values[lane * HWd + pix];

    float sim_sum = 0.f;
    float w_sum = 1e-5f;

    for (int v = 0; v < 4; ++v) {
        const float* __restrict__ src = features + (v + 1) * Cd * HWd;
        const float* m = &sm[WS_ROT + v * 12];
        const float rX = m[0] * xf + m[1] * yf + m[2];
        const float rY = m[3] * xf + m[4] * yf + m[5];
        const float rZ = m[6] * xf + m[7] * yf + m[8];
        const float X = rX * dep + m[9];
        const float Y = rY * dep + m[10];
        const float Z = rZ * dep + m[11];
        const float pxf = X / Z;
        const float pyf = Y / Z;
        const float fx0 = floorf(pxf), fy0 = floorf(pyf);
        const float wx1 = pxf - fx0, wy1 = pyf - fy0;
        const float wx0 = 1.f - wx1, wy0 = 1.f - wy1;
        const float fx1 = fx0 + 1.f, fy1 = fy0 + 1.f;
        const float bx0 = (fx0 >= 0.f && fx0 <= (float)(Wd - 1)) ? 1.f : 0.f;
        const float bx1 = (fx1 >= 0.f && fx1 <= (float)(Wd - 1)) ? 1.f : 0.f;
        const float by0 = (fy0 >= 0.f && fy0 <= (float)(Hd - 1)) ? 1.f : 0.f;
        const float by1 = (fy1 >= 0.f && fy1 <= (float)(Hd - 1)) ? 1.f : 0.f;
        const float w00 = wx0 * wy0 * bx0 * by0;
        const float w01 = wx1 * wy0 * bx1 * by0;
        const float w10 = wx0 * wy1 * bx0 * by1;
        const float w11 = wx1 * wy1 * bx1 * by1;
        const int ix0 = (int)fminf(fmaxf(fx0, 0.f), (float)(Wd - 1));
        const int ix1 = (int)fminf(fmaxf(fx1, 0.f), (float)(Wd - 1));
        const int iy0 = (int)fminf(fmaxf(fy0, 0.f), (float)(Hd - 1));
        const int iy1 = (int)fminf(fmaxf(fy1, 0.f), (float)(Hd - 1));
        const int i00 = iy0 * Wd + ix0;
        const int i01 = iy0 * Wd + ix1;
        const int i10 = iy1 * Wd + ix0;
        const int i11 = iy1 * Wd + ix1;

        float acc = 0.f;
#pragma unroll
        for (int c = 0; c < Cd; ++c) {
            const float* p = src + c * HWd;
            const float bil = p[i00] * w00 + p[i01] * w01 + p[i10] * w10 + p[i11] * w11;
            acc += bil * refc[c];
        }
        const float sim = acc * (1.f / 32.f);

        float x0v[16];
#pragma unroll
        for (int j = 0; j < 16; ++j)
            x0v[j] = fmaxf(sm[WS_A0 + j] * sim + sm[WS_B0 + j], 0.f);
        float yv = sm[WS_BIAS2];
#pragma unroll
        for (int k = 0; k < 8; ++k) {
            float d0 = 0.f;
#pragma unroll
            for (int j = 0; j < 16; ++j) d0 += sm[WS_W1 + k * 16 + j] * x0v[j];
            const float x1 = fmaxf(d0 + sm[WS_B1 + k], 0.f);
            yv += sm[WS_W2 + k] * x1;
        }
        float ymax = yv;
#pragma unroll
        for (int o = 32; o >= 1; o >>= 1) ymax = fmaxf(ymax, __shfl_xor(ymax, o, 64));
        const float vw = 1.f / (1.f + expf(-ymax));
        sim_sum += sim * vw;
        w_sum += vw;
        if (lane == 0) out[VW_OFF + v * HWd + pix] = vw;
    }

    const float simil = sim_sum / w_sum;

    float bv = simil; int bi = lane;
#pragma unroll
    for (int o = 32; o >= 1; o >>= 1) {
        const float ov = __shfl_xor(bv, o, 64);
        const int oi = __shfl_xor(bi, o, 64);
        if (ov > bv || (ov == bv && oi < bi)) { bv = ov; bi = oi; }
    }
    const float sim_depth = __shfl(dep, bi, 64);

    float y2 = sm[WS_CB1];
#pragma unroll
    for (int j = 0; j < 8; ++j) {
        const float h = fmaxf(sm[WS_CW0 + j] * simil + sm[WS_CB0 + j], 0.f);
        y2 += sm[WS_CW1 + j] * h;
    }
    float m2 = y2;
#pragma unroll
    for (int o = 32; o >= 1; o >>= 1) m2 = fmaxf(m2, __shfl_xor(m2, o, 64));
    const float e = expf(y2 - m2);
    float s = e;
#pragma unroll
    for (int o = 32; o >= 1; o >>= 1) s += __shfl_xor(s, o, 64);
    const float prob = e / s;
    out[PV_OFF + lane * HWd + pix] = prob;

    float bv2 = y2; int bi2 = lane;
#pragma unroll
    for (int o = 32; o >= 1; o >>= 1) {
        const float ov = __shfl_xor(bv2, o, 64);
        const int oi = __shfl_xor(bi2, o, 64);
        if (ov > bv2 || (ov == bv2 && oi < bi2)) { bv2 = ov; bi2 = oi; }
    }
    const float depth_o = __shfl(dep, bi2, 64);
    const float conf = 1.f / s;

    if (lane == 0) {
        out[pix] = depth_o;
        out[HWd + pix] = sim_depth;
        out[2 * HWd + pix] = conf;
    }
}

extern "C" void kernel_launch(void* const* d_in, const int* in_sizes, int n_in,
                              void* d_out, int out_size, void* d_ws, size_t ws_size,
                              hipStream_t stream)
{
    const float* features     = (const float*)d_in[0];
    const float* pm           = (const float*)d_in[1];
    const float* depth_values = (const float*)d_in[2];
    const float* pw_w0   = (const float*)d_in[4];
    const float* pw_g0   = (const float*)d_in[5];
    const float* pw_b0   = (const float*)d_in[6];
    const float* pw_w1   = (const float*)d_in[7];
    const float* pw_g1   = (const float*)d_in[8];
    const float* pw_b1   = (const float*)d_in[9];
    const float* pw_w2   = (const float*)d_in[10];
    const float* pw_bias2= (const float*)d_in[11];
    const float* cr_w0   = (const float*)d_in[12];
    const float* cr_b0   = (const float*)d_in[13];
    const float* cr_w1   = (const float*)d_in[14];
    const float* cr_b1   = (const float*)d_in[15];
    float* wsf = (float*)d_ws;
    float* out = (float*)d_out;

    hipLaunchKernelGGL(setup_kernel, dim3(1), dim3(64), 0, stream,
                       pm, pw_w0, pw_g0, pw_b0, pw_w1, pw_g1, pw_b1, pw_w2, pw_bias2,
                       cr_w0, cr_b0, cr_w1, cr_b1, wsf);

    const size_t need = (size_t)WS_FEAT_OFF * 4 + (size_t)5 * HWd * Cd * 4;
    if (ws_size >= need) {
        float* featT = wsf + WS_FEAT_OFF;
        hipLaunchKernelGGL(lut_kernel, dim3(LUT_N / 256), dim3(256), 0, stream,
                           pw_w0, pw_g0, pw_b0, pw_w1, pw_g1, pw_b1, pw_w2, pw_bias2, wsf);
        hipLaunchKernelGGL(transpose_kernel, dim3(HWd / 128, 5), dim3(256), 0, stream,
                           features, featT);
        hipLaunchKernelGGL(depthnet_main_t, dim3(HWd / 4), dim3(256), 0, stream,
                           featT, depth_values, wsf, out);
    } else {
        hipLaunchKernelGGL(depthnet_main, dim3(HWd / 4), dim3(256), 0, stream,
                           features, depth_values, wsf, out);
    }
}